// Round 12
// baseline (139.158 us; speedup 1.0000x reference)
//
#include <hip/hip_runtime.h>
#include <hip/hip_bf16.h>

__device__ __forceinline__ float sigm(float x) { return 1.0f / (1.0f + __expf(-x)); }

// Workspace float layout:
#define WS_WCM   0      // [2][20][20] = 800   w_comb * relu(yc) per mask value
#define WS_BCOMB 800    // 20
#define WS_WFIN  820    // 20
#define WS_BFIN  840    // 1
#define WS_SAB   1024   // [8][B][40]: per (phase,batch): SA[0..20) SB[20..40)
                        //   SA = YA[k0]+YA[k1], SB = YB[k0]+YB[k1]  (21 MB)

// ---------------- k1: pre-pass, source-coalesced --------------------------
// Grid = 8 * B/256 blocks of 256. Block = (ph, 256-batch chunk). Per block:
// build YA/YB 60-key tables in LDS (R3 preamble), then each thread reads its
// own 64B feat row (L1-windowed), computes the 2 keys for ph's lanes, and
// writes the combined 40-float SA|SB row contiguously. Block 0 additionally
// writes WCM (w_comb * relu(yc)) and scalars to ws.
__global__ __launch_bounds__(256) void frap_pre(
    const float* __restrict__ feat,
    const float* __restrict__ emb_phase, const float* __restrict__ w_veh,
    const float* __restrict__ b_veh,     const float* __restrict__ w_line,
    const float* __restrict__ b_line,    const float* __restrict__ emb_const,
    const float* __restrict__ w_feat,    const float* __restrict__ b_feat,
    const float* __restrict__ w_const,   const float* __restrict__ b_const,
    const float* __restrict__ w_comb,    const float* __restrict__ b_comb,
    const float* __restrict__ w_final,   const float* __restrict__ b_final,
    float* __restrict__ ws, int B)
{
    __shared__ __align__(16) float s_y[2400];   // [0,1200)=YA  [1200,2400)=YB
    __shared__ float s_stage[820];

    const int tid = threadIdx.x;

    // ---- stage tiny weights ----
    for (int k = tid; k < 128; k += 256) s_stage[k] = w_line[k];
    for (int k = tid; k < 640; k += 256) s_stage[128 + k] = w_feat[k];
    if (tid < 16)                s_stage[768 + tid] = b_line[tid];
    if (tid < 4)                 s_stage[784 + tid] = w_veh[tid];
    if (tid >= 4 && tid < 8)     s_stage[784 + tid] = b_veh[tid - 4];
    if (tid >= 8 && tid < 16)    s_stage[784 + tid] = emb_phase[tid - 8];
    if (tid >= 16 && tid < 36)   s_stage[784 + tid] = b_feat[tid - 16];
    __syncthreads();

    // ---- build YA/YB tables: 240 threads, 4 per key ----
    if (tid < 240) {
        int key = tid >> 2, part = tid & 3;
        int veh = key >> 1, pb = key & 1;
        float vf = (float)veh;
        float line[8];
#pragma unroll
        for (int k = 0; k < 4; k++) line[k] = sigm(fmaf(vf, s_stage[784 + k], s_stage[788 + k]));
#pragma unroll
        for (int k = 0; k < 4; k++) line[4 + k] = sigm(s_stage[792 + pb * 4 + k]);
        float X[16];
#pragma unroll
        for (int o = 0; o < 16; o++) {
            float x = s_stage[768 + o];
#pragma unroll
            for (int d = 0; d < 8; d++) x = fmaf(line[d], s_stage[o * 8 + d], x);
            X[o] = fmaxf(x, 0.f);
        }
        int o0 = part * 5;
#pragma unroll
        for (int oo = 0; oo < 5; oo++) {
            int o = o0 + oo;
            float a = 0.25f * s_stage[800 + o];
            float bb = a;
#pragma unroll
            for (int c = 0; c < 16; c++) {
                a  = fmaf(X[c], s_stage[128 + o * 32 + c], a);
                bb = fmaf(X[c], s_stage[128 + o * 32 + 16 + c], bb);
            }
            s_y[key * 20 + o] = a;
            s_y[1200 + key * 20 + o] = bb;
        }
    }
    __syncthreads();

    // ---- per-thread: combined SA|SB row for (ph, b) ----
    const int bpp = B >> 8;                        // blocks per phase
    const int ph = blockIdx.x / bpp;               // 0..7 (block-uniform)
    const int b = (blockIdx.x - ph * bpp) * 256 + tid;

    const unsigned L0T = 0x64204051u, L1T = 0x75316273u;
    const int l0 = (L0T >> (ph * 4)) & 15, l1 = (L1T >> (ph * 4)) & 15;
    const float* row = feat + (size_t)b * 16;
    int k0 = min(59, max(0, (int)fmaf(row[8 + l0], 2.f, row[l0])));
    int k1 = min(59, max(0, (int)fmaf(row[8 + l1], 2.f, row[l1])));

    const float4* A0 = (const float4*)(s_y + k0 * 20);
    const float4* A1 = (const float4*)(s_y + k1 * 20);
    const float4* B0 = (const float4*)(s_y + 1200 + k0 * 20);
    const float4* B1 = (const float4*)(s_y + 1200 + k1 * 20);

    float4* dst = (float4*)(ws + WS_SAB + ((size_t)ph * B + b) * 40);
#pragma unroll
    for (int r = 0; r < 5; r++) {
        float4 a0 = A0[r], a1 = A1[r];
        float4 sa; sa.x = a0.x + a1.x; sa.y = a0.y + a1.y;
        sa.z = a0.z + a1.z; sa.w = a0.w + a1.w;
        dst[r] = sa;
    }
#pragma unroll
    for (int r = 0; r < 5; r++) {
        float4 c0 = B0[r], c1 = B1[r];
        float4 sb; sb.x = c0.x + c1.x; sb.y = c0.y + c1.y;
        sb.z = c0.z + c1.z; sb.w = c0.w + c1.w;
        dst[5 + r] = sb;
    }

    // ---- block 0: WCM + scalars ----
    if (blockIdx.x == 0) {
        for (int idx = tid; idx < 800; idx += 256) {
            int m = idx / 400;
            int r = idx - m * 400;
            int q = r / 20;
            int o = r - q * 20;
            float yc = b_const[o];
#pragma unroll
            for (int k = 0; k < 4; k++)
                yc = fmaf(w_const[o * 4 + k], emb_const[m * 4 + k], yc);
            ws[WS_WCM + idx] = w_comb[q * 20 + o] * fmaxf(yc, 0.f);
        }
        if (tid < 20) { ws[WS_BCOMB + tid] = b_comb[tid]; ws[WS_WFIN + tid] = w_final[tid]; }
        if (tid == 0) ws[WS_BFIN] = b_final[0];
    }
}

// ---------------- k2: main -------------------------------------------------
// 448-thread blocks = 7 waves. Block = (phase i, 64-bp chunk); wave jw = j.
// No LDS tables: xf = relu(SA[pi][b] + SB[pj][b]) from 10 global dwordx4
// (L2-hot). Mask bit (i,jw)-uniform -> scalar W base; W rows via uniform
// s_load. Partials combined via s_part in j-order (reference sum order).
__global__ __launch_bounds__(448, 4) void frap_main(
    const int* __restrict__ cmask,
    const float* __restrict__ ws, float* __restrict__ out, int B)
{
    __shared__ float s_part[448];

    const int tid = threadIdx.x;
    const int i = blockIdx.x & 7;
    const int chunk = blockIdx.x >> 3;
    const int lane = tid & 63;
    const int jw = __builtin_amdgcn_readfirstlane(tid >> 6);   // 0..6 scalar
    const int bp = (chunk << 6) + lane;
    const bool valid = bp < B;
    const int bpc = valid ? bp : 0;

    const int mbit = __builtin_amdgcn_readfirstlane(cmask[i * 7 + jw]) & 1;
    const float* wbase = ws + WS_WCM + (mbit ? 400 : 0);

    const unsigned Bu = (unsigned)B;
    const unsigned g = 56u * (unsigned)bpc + 7u * (unsigned)i + (unsigned)jw;
    const unsigned p = g / Bu;
    const unsigned b = g - p * Bu;
    const unsigned pi = p / 7u;
    const unsigned c7 = p - pi * 7u;
    const unsigned pj = c7 + (c7 >= pi ? 1u : 0u);

    const float4* sa = (const float4*)(ws + WS_SAB + ((size_t)pi * Bu + b) * 40);
    const float4* sb = (const float4*)(ws + WS_SAB + ((size_t)pj * Bu + b) * 40 + 20);

    float xf[20];
#pragma unroll
    for (int r = 0; r < 5; r++) {
        float4 a = sa[r], c = sb[r];
        xf[4 * r + 0] = fmaxf(a.x + c.x, 0.f);
        xf[4 * r + 1] = fmaxf(a.y + c.y, 0.f);
        xf[4 * r + 2] = fmaxf(a.z + c.z, 0.f);
        xf[4 * r + 3] = fmaxf(a.w + c.w, 0.f);
    }

    float acc = 0.f;
    for (int q = 0; q < 20; q++) {
        const float4* wr = (const float4*)(wbase + q * 20);   // uniform -> s_load
        float4 w0 = wr[0], w1 = wr[1], w2 = wr[2], w3 = wr[3], w4 = wr[4];
        float h = ws[WS_BCOMB + q];
        h = fmaf(w0.x, xf[0],  h); h = fmaf(w0.y, xf[1],  h);
        h = fmaf(w0.z, xf[2],  h); h = fmaf(w0.w, xf[3],  h);
        h = fmaf(w1.x, xf[4],  h); h = fmaf(w1.y, xf[5],  h);
        h = fmaf(w1.z, xf[6],  h); h = fmaf(w1.w, xf[7],  h);
        h = fmaf(w2.x, xf[8],  h); h = fmaf(w2.y, xf[9],  h);
        h = fmaf(w2.z, xf[10], h); h = fmaf(w2.w, xf[11], h);
        h = fmaf(w3.x, xf[12], h); h = fmaf(w3.y, xf[13], h);
        h = fmaf(w3.z, xf[14], h); h = fmaf(w3.w, xf[15], h);
        h = fmaf(w4.x, xf[16], h); h = fmaf(w4.y, xf[17], h);
        h = fmaf(w4.z, xf[18], h); h = fmaf(w4.w, xf[19], h);
        acc = fmaf(ws[WS_WFIN + q], fmaxf(h, 0.f), acc);
    }
    float val = fmaxf(acc + ws[WS_BFIN], 0.f);

    s_part[tid] = val;
    __syncthreads();
    if (jw == 0 && valid) {
        float total = val;                     // j = 0
#pragma unroll
        for (int w = 1; w < 7; w++)            // j = 1..6 in order
            total += s_part[lane + (w << 6)];
        out[(size_t)bp * 8 + i] = total;
    }
}

extern "C" void kernel_launch(void* const* d_in, const int* in_sizes, int n_in,
                              void* d_out, int out_size, void* d_ws, size_t ws_size,
                              hipStream_t stream) {
    const float* feat      = (const float*)d_in[0];
    const float* emb_phase = (const float*)d_in[1];
    const float* w_veh     = (const float*)d_in[2];
    const float* b_veh     = (const float*)d_in[3];
    const float* w_line    = (const float*)d_in[4];
    const float* b_line    = (const float*)d_in[5];
    const float* emb_const = (const float*)d_in[6];
    const float* w_feat    = (const float*)d_in[7];
    const float* b_feat    = (const float*)d_in[8];
    const float* w_const   = (const float*)d_in[9];
    const float* b_const   = (const float*)d_in[10];
    const float* w_comb    = (const float*)d_in[11];
    const float* b_comb    = (const float*)d_in[12];
    const float* w_final   = (const float*)d_in[13];
    const float* b_final   = (const float*)d_in[14];
    const int*   cmask     = (const int*)d_in[15];

    int B = in_sizes[0] / 16;                 // 16384
    float* ws = (float*)d_ws;

    int pre_blocks = 8 * (B >> 8);            // 512
    frap_pre<<<pre_blocks, 256, 0, stream>>>(feat, emb_phase, w_veh, b_veh,
                                             w_line, b_line, emb_const,
                                             w_feat, b_feat, w_const, b_const,
                                             w_comb, b_comb, w_final, b_final,
                                             ws, B);
    int blocks = 8 * ((B + 63) / 64);         // 2048
    frap_main<<<blocks, 448, 0, stream>>>(cmask, ws, (float*)d_out, B);
}